// Round 7
// baseline (4186.108 us; speedup 1.0000x reference)
//
#include <hip/hip_runtime.h>
#include <hip/hip_bf16.h>

// GRU forward: B=64, T=512, I=512, U=512, out [B,T,U] fp32.
// Round 7: dataflow restructure of the scan. 64 persistent WGs = 4 groups
// (16 batch rows) x 16 col-WGs (32 units). R-slice per WG in regs (hi/lo bf16
// planes, 3-MFMA compensated product). NEW protocol (vs r2-r6's 3 barriers +
// tid0 relay, all stuck at ~6.4us/step):
//   waves 0-5 (MFMA): poll all 32 peer half-flags DIRECTLY (lanes 0-31,
//     __all), then bulk-load h + 48 MFMA in one straight-line block, write
//     pre[parity] to LDS. ONE __syncthreads. No relay, no staging.
//   waves 6-7 (gates, 4 units/thread): read pre[parity]+xsh[parity], compute
//     h_t, 2x u64 sc1 stores, OWN-WAVE vmcnt(0) drain, per-wave flag (2 flags
//     per WG -> no cross-wave handshake), THEN x[t+1] prefetch to regs, out
//     store, ds_write xsh[parity^1]. Release is ahead of all bulk traffic.
// Safety: flags monotone; flag>=t+1 from a peer certifies it passed its
// barrier(t) and finished consuming parity-t buffers (pre/hbuf WAR safe).
// 64 WGs always co-resident -> polls cannot deadlock. h=0 start: hbuf+flags
// pre-zeroed; poll at t=0 passes trivially (flags>=0).

typedef float f32x4 __attribute__((ext_vector_type(4)));
typedef short bf16x8 __attribute__((ext_vector_type(8)));
typedef unsigned long long u64;
typedef unsigned int u32;

#define MFMA16(a, b, c) __builtin_amdgcn_mfma_f32_16x16x32_bf16((a), (b), (c), 0, 0, 0)

__device__ __forceinline__ float bf2f(__hip_bfloat16 v) { return __bfloat162float(v); }

__device__ __forceinline__ void split_bf(float v, short& hi, short& lo) {
    __hip_bfloat16 h = __float2bfloat16(v);
    float rem = v - __bfloat162float(h);
    __hip_bfloat16 l = __float2bfloat16(rem);
    hi = __builtin_bit_cast(short, h);
    lo = __builtin_bit_cast(short, l);
}

struct U64x2 {
    u64 a, b;
};

// Device-coherent 16B load as two sc1 dwordx2 loads (agent scope, relaxed).
__device__ __forceinline__ bf16x8 load_frag_sc1(const __hip_bfloat16* p) {
    const u64* q = (const u64*)p;
    U64x2 t;
    t.a = __hip_atomic_load(q, __ATOMIC_RELAXED, __HIP_MEMORY_SCOPE_AGENT);
    t.b = __hip_atomic_load(q + 1, __ATOMIC_RELAXED, __HIP_MEMORY_SCOPE_AGENT);
    return __builtin_bit_cast(bf16x8, t);
}

// ---------------------------------------------------------------- zero scratch
__global__ void zero_kernel(float* p, int n) {
    int i = blockIdx.x * blockDim.x + threadIdx.x;
    int stride = gridDim.x * blockDim.x;
    for (; i < n; i += stride) p[i] = 0.f;
}

// ------------------------------------------------- pack weights into B-frags
// Source W [512 x 1536] fp32. Frag (tile,kk): lane l element e =
// W[kk*32 + 8*(l>>4) + e][tile*16 + (l&15)], stored hi/lo bf16 planes.
__global__ __launch_bounds__(64, 1) void pack_w_kernel(const float* __restrict__ W,
                                                       short* __restrict__ dhi,
                                                       short* __restrict__ dlo) {
    int bid = blockIdx.x;   // tile*16 + kk, 0..1535
    int lane = threadIdx.x; // 0..63
    int col = (bid >> 4) * 16 + (lane & 15);
    int kbase = (bid & 15) * 32 + (lane >> 4) * 8;
    bf16x8 vh, vl;
#pragma unroll
    for (int e = 0; e < 8; e++) {
        float v = W[(kbase + e) * 1536 + col];
        short h, l;
        split_bf(v, h, l);
        vh[e] = h;
        vl[e] = l;
    }
    *(bf16x8*)(dhi + bid * 512 + lane * 8) = vh;
    *(bf16x8*)(dlo + bid * 512 + lane * 8) = vl;
}

// ------------------------------------------------------------- x_all GEMM
__global__ __launch_bounds__(256, 2) void xgemm_kernel(
    const float* __restrict__ A, const short* __restrict__ wkh,
    const short* __restrict__ wkl, const float* __restrict__ bias,
    __hip_bfloat16* __restrict__ xhi, __hip_bfloat16* __restrict__ xlo, int xlo_en) {
    int rt = blockIdx.x; // 0..2047
    int wave = threadIdx.x >> 6, lane = threadIdx.x & 63;
    int arow = rt * 16 + (lane & 15);
    const float* abase = A + arow * 512 + (lane >> 4) * 8;

    f32x4 acc[24];
#pragma unroll
    for (int j = 0; j < 24; j++) acc[j] = (f32x4){0.f, 0.f, 0.f, 0.f};

#pragma unroll 1
    for (int kk = 0; kk < 16; kk++) {
        f32x4 a0 = *(const f32x4*)(abase + kk * 32);
        f32x4 a1 = *(const f32x4*)(abase + kk * 32 + 4);
        bf16x8 ah, al;
#pragma unroll
        for (int e = 0; e < 8; e++) {
            float v = (e < 4) ? a0[e] : a1[e - 4];
            short h, l;
            split_bf(v, h, l);
            ah[e] = h;
            al[e] = l;
        }
#pragma unroll
        for (int j = 0; j < 24; j++) {
            int frag = (wave * 24 + j) * 16 + kk;
            bf16x8 bh = *(const bf16x8*)(wkh + frag * 512 + lane * 8);
            bf16x8 bl = *(const bf16x8*)(wkl + frag * 512 + lane * 8);
            acc[j] = MFMA16(ah, bh, acc[j]);
            acc[j] = MFMA16(al, bh, acc[j]);
            acc[j] = MFMA16(ah, bl, acc[j]);
        }
    }
    int colin = lane & 15, r4 = (lane >> 4) * 4;
#pragma unroll
    for (int j = 0; j < 24; j++) {
        int colg = (wave * 24 + j) * 16 + colin;
        float bv = bias[colg];
#pragma unroll
        for (int r = 0; r < 4; r++) {
            float v = acc[j][r] + bv;
            int rowg = rt * 16 + r4 + r;
            short h, l;
            split_bf(v, h, l);
            xhi[rowg * 1536 + colg] = __builtin_bit_cast(__hip_bfloat16, h);
            if (xlo_en) xlo[rowg * 1536 + colg] = __builtin_bit_cast(__hip_bfloat16, l);
        }
    }
}

// ------------------------------------------------------------------ scan
__global__ __launch_bounds__(512, 2) void scan_kernel(
    const __hip_bfloat16* __restrict__ xhi, const __hip_bfloat16* __restrict__ xlo,
    const short* __restrict__ wrh, const short* __restrict__ wrl,
    const float* __restrict__ bias, float* __restrict__ out,
    __hip_bfloat16* hbuf, int* flags, int xlo_en) {
    const int bid = blockIdx.x;
    const int g = bid & 3;
    const int w = bid >> 2;
    const int tid = threadIdx.x;
    const int wave = tid >> 6;
    const int lane = tid & 63;

    __shared__ __align__(16) float pre[2][6][16][16];           // parity-doubled
    __shared__ __align__(16) __hip_bfloat16 xsh[2][2][16][104]; // [par][plane]
    __shared__ float rb[96];

    if (tid < 96) rb[tid] = bias[1536 + (tid >> 5) * 512 + w * 32 + (tid & 31)];

    // persistent B fragments (hi+lo) for waves 0-5
    bf16x8 bh[16], bl[16];
    if (wave < 6) {
        int tile = (wave >> 1) * 32 + 2 * w + (wave & 1);
#pragma unroll
        for (int kk = 0; kk < 16; kk++) {
            bh[kk] = *(const bf16x8*)(wrh + (tile * 16 + kk) * 512 + lane * 8);
            bl[kk] = *(const bf16x8*)(wrl + (tile * 16 + kk) * 512 + lane * 8);
        }
#pragma unroll
        for (int kk = 0; kk < 16; kk++) {
            asm volatile("" : "+v"(bh[kk]), "+v"(bl[kk]));
        }
    } else {
        // x[0] prefetch straight into xsh[0]
        int it0 = tid - 384; // 0..127
        int nch = xlo_en ? 384 : 192;
        for (int c = it0; c < nch; c += 128) {
            int plane = c / 192, rem = c % 192;
            int row_ = rem / 12, cw = rem % 12;
            int seg = cw >> 2, off = cw & 3;
            const __hip_bfloat16* src = (plane ? xlo : xhi) +
                                        (size_t)((g * 16 + row_) * 512) * 1536 +
                                        seg * 512 + w * 32 + off * 8;
            *(bf16x8*)&xsh[0][plane][row_][seg * 32 + off * 8] = *(const bf16x8*)src;
        }
    }

    // gate-thread mapping (waves 6-7): 4 units x 1 row per thread
    const int it = tid - 384;          // 0..127 when wave>=6
    const int wv = (it >> 6) & 1;      // 0 = wave6, 1 = wave7
    const int idx = it & 63;           // lane within gate wave
    const int gr = (idx & 7) + 8 * wv; // batch row 0..15
    const int jj = (idx >> 3) * 4;     // unit base {0,4,...,28}
    float hreg0 = 0.f, hreg1 = 0.f, hreg2 = 0.f, hreg3 = 0.f;

    __syncthreads();

    const int HB = 8192; // plane stride (elems)
    for (int t = 0; t < 512; t++) {
        const int par = t & 1;
        if (wave < 6) {
            // ---- direct poll: all 32 half-flags >= t ----
            {
                long spins = 0;
                while (true) {
                    int f = 0x7fffffff;
                    if (lane < 32)
                        f = __hip_atomic_load(
                            &flags[((g * 16 + (lane >> 1)) * 2 + (lane & 1)) * 16],
                            __ATOMIC_RELAXED, __HIP_MEMORY_SCOPE_AGENT);
                    if (__all(f >= t)) break;
                    if (++spins > (1L << 22)) break; // bailout (never hit if correct)
                }
            }
            // ---- bulk load + MFMA, single straight-line block ----
            const __hip_bfloat16* hH = hbuf + (par * 4 + g) * 2 * HB;
            const __hip_bfloat16* hL = hH + HB;
            f32x4 aa = (f32x4){0.f, 0.f, 0.f, 0.f};
            f32x4 ab = (f32x4){0.f, 0.f, 0.f, 0.f};
            f32x4 ac = (f32x4){0.f, 0.f, 0.f, 0.f};
#pragma unroll
            for (int kk = 0; kk < 16; kk++) {
                bf16x8 ah = load_frag_sc1(hH + kk * 512 + lane * 8);
                bf16x8 al = load_frag_sc1(hL + kk * 512 + lane * 8);
                aa = MFMA16(ah, bh[kk], aa);
                ab = MFMA16(al, bh[kk], ab);
                ac = MFMA16(ah, bl[kk], ac);
            }
            f32x4 acc = aa + ab;
            acc = acc + ac;
            *(f32x4*)&pre[par][wave][lane & 15][(lane >> 4) * 4] = acc;
        }
        __syncthreads(); // the ONLY barrier per step: pre[par] ready
        if (wave >= 6) {
            // ---- gates: 4 units, one row ----
            f32x4 hn;
            float hold[4] = {hreg0, hreg1, hreg2, hreg3};
#pragma unroll
            for (int i = 0; i < 4; i++) {
                int uu = jj + i;
                float xz = bf2f(xsh[par][0][gr][uu]);
                float xr = bf2f(xsh[par][0][gr][32 + uu]);
                float xh = bf2f(xsh[par][0][gr][64 + uu]);
                if (xlo_en) {
                    xz += bf2f(xsh[par][1][gr][uu]);
                    xr += bf2f(xsh[par][1][gr][32 + uu]);
                    xh += bf2f(xsh[par][1][gr][64 + uu]);
                }
                float rz = pre[par][(uu >> 4)][uu & 15][gr] + rb[uu];
                float rr = pre[par][2 + (uu >> 4)][uu & 15][gr] + rb[32 + uu];
                float rh = pre[par][4 + (uu >> 4)][uu & 15][gr] + rb[64 + uu];
                float z = 1.f / (1.f + expf(-(xz + rz)));
                float r = 1.f / (1.f + expf(-(xr + rr)));
                float hh = tanhf(xh + r * rh);
                hn[i] = z * hold[i] + (1.f - z) * hh;
            }
            hreg0 = hn[0];
            hreg1 = hn[1];
            hreg2 = hn[2];
            hreg3 = hn[3];
            if (t < 511) {
                // ---- release path FIRST: h stores + own drain + per-wave flag
                short h4[4], l4[4];
#pragma unroll
                for (int i = 0; i < 4; i++) split_bf(hn[i], h4[i], l4[i]);
                u64 vh = (u64)(unsigned short)h4[0] | ((u64)(unsigned short)h4[1] << 16) |
                         ((u64)(unsigned short)h4[2] << 32) |
                         ((u64)(unsigned short)h4[3] << 48);
                u64 vl = (u64)(unsigned short)l4[0] | ((u64)(unsigned short)l4[1] << 16) |
                         ((u64)(unsigned short)l4[2] << 32) |
                         ((u64)(unsigned short)l4[3] << 48);
                __hip_bfloat16* dst = hbuf + (((par ^ 1) * 4 + g) * 2) * HB + w * 512 +
                                      (gr + 16 * (jj >> 3)) * 8 + (jj & 7);
                __hip_atomic_store((u64*)dst, vh, __ATOMIC_RELAXED,
                                   __HIP_MEMORY_SCOPE_AGENT);
                __hip_atomic_store((u64*)(dst + HB), vl, __ATOMIC_RELAXED,
                                   __HIP_MEMORY_SCOPE_AGENT);
                asm volatile("s_waitcnt vmcnt(0)" ::: "memory"); // own stores ack'd
                if (idx == 0)
                    __hip_atomic_store(&flags[((g * 16 + w) * 2 + wv) * 16], t + 1,
                                       __ATOMIC_RELAXED, __HIP_MEMORY_SCOPE_AGENT);
                // ---- post-release: x[t+1] prefetch -> regs ----
                int nch = xlo_en ? 384 : 192;
                bf16x8 xv0, xv1, xv2;
                int c0 = it, c1 = it + 128, c2 = it + 256;
                {
                    int plane = c0 / 192, rem = c0 % 192, row_ = rem / 12, cw = rem % 12;
                    const __hip_bfloat16* src =
                        (plane ? xlo : xhi) +
                        (size_t)((g * 16 + row_) * 512 + (t + 1)) * 1536 +
                        (cw >> 2) * 512 + w * 32 + (cw & 3) * 8;
                    xv0 = *(const bf16x8*)src;
                }
                {
                    int plane = c1 / 192, rem = c1 % 192, row_ = rem / 12, cw = rem % 12;
                    const __hip_bfloat16* src =
                        (plane ? xlo : xhi) +
                        (size_t)((g * 16 + row_) * 512 + (t + 1)) * 1536 +
                        (cw >> 2) * 512 + w * 32 + (cw & 3) * 8;
                    xv1 = *(const bf16x8*)src;
                }
                if (c2 < nch) {
                    int plane = c2 / 192, rem = c2 % 192, row_ = rem / 12, cw = rem % 12;
                    const __hip_bfloat16* src =
                        (plane ? xlo : xhi) +
                        (size_t)((g * 16 + row_) * 512 + (t + 1)) * 1536 +
                        (cw >> 2) * 512 + w * 32 + (cw & 3) * 8;
                    xv2 = *(const bf16x8*)src;
                }
                // out store (overlaps x-load latency)
                *(f32x4*)&out[((size_t)(g * 16 + gr) * 512 + t) * 512 + w * 32 + jj] =
                    hn;
                // ds_write xsh[par^1] (compiler waits the x loads)
                {
                    int plane = c0 / 192, rem = c0 % 192, row_ = rem / 12, cw = rem % 12;
                    *(bf16x8*)&xsh[par ^ 1][plane][row_][(cw >> 2) * 32 + (cw & 3) * 8] =
                        xv0;
                }
                {
                    int plane = c1 / 192, rem = c1 % 192, row_ = rem / 12, cw = rem % 12;
                    *(bf16x8*)&xsh[par ^ 1][plane][row_][(cw >> 2) * 32 + (cw & 3) * 8] =
                        xv1;
                }
                if (c2 < nch) {
                    int plane = c2 / 192, rem = c2 % 192, row_ = rem / 12, cw = rem % 12;
                    *(bf16x8*)&xsh[par ^ 1][plane][row_][(cw >> 2) * 32 + (cw & 3) * 8] =
                        xv2;
                }
            } else {
                *(f32x4*)&out[((size_t)(g * 16 + gr) * 512 + t) * 512 + w * 32 + jj] =
                    hn;
            }
        }
    }
}

extern "C" void kernel_launch(void* const* d_in, const int* in_sizes, int n_in,
                              void* d_out, int out_size, void* d_ws, size_t ws_size,
                              hipStream_t stream) {
    const float* inputs = (const float*)d_in[0]; // [64,512,512]
    const float* wk = (const float*)d_in[1];     // [512,1536]
    const float* wr = (const float*)d_in[2];     // [512,1536]
    const float* bias = (const float*)d_in[3];   // [2,1536]
    float* out = (float*)d_out;
    char* ws = (char*)d_ws;

    const size_t SZ_W = 512UL * 1536 * 2; // 1.5 MiB per plane
    short* wk_hi = (short*)(ws);
    short* wk_lo = (short*)(ws + SZ_W);
    short* wr_hi = (short*)(ws + 2 * SZ_W);
    short* wr_lo = (short*)(ws + 3 * SZ_W);
    __hip_bfloat16* hbuf = (__hip_bfloat16*)(ws + 4 * SZ_W); // 256 KiB
    int* flags = (int*)(ws + 4 * SZ_W + 262144);             // 8 KiB (128 x 64B)
    char* xbase = ws + 4 * SZ_W + 262144 + 8192;
    const size_t SZ_X = 32768UL * 1536 * 2; // 96 MiB per plane
    __hip_bfloat16* xhi = (__hip_bfloat16*)xbase;
    __hip_bfloat16* xlo = (__hip_bfloat16*)(xbase + SZ_X);

    size_t need_min = (size_t)(xbase - ws) + SZ_X;
    size_t need_full = need_min + SZ_X;
    if (ws_size < need_min) return; // cannot run without scratch; fail visibly
    int xlo_en = (ws_size >= need_full) ? 1 : 0;

    zero_kernel<<<256, 256, 0, stream>>>((float*)hbuf, (262144 + 8192) / 4);
    pack_w_kernel<<<1536, 64, 0, stream>>>(wk, wk_hi, wk_lo);
    pack_w_kernel<<<1536, 64, 0, stream>>>(wr, wr_hi, wr_lo);
    xgemm_kernel<<<2048, 256, 0, stream>>>(inputs, wk_hi, wk_lo, bias, xhi, xlo, xlo_en);
    scan_kernel<<<64, 512, 0, stream>>>(xhi, xlo, wr_hi, wr_lo, bias, out, hbuf, flags,
                                        xlo_en);
}

// Round 8
// 3079.325 us; speedup vs baseline: 1.3594x; 1.3594x over previous
//
#include <hip/hip_runtime.h>
#include <hip/hip_bf16.h>

// GRU forward: B=64, T=512, I=512, U=512, out [B,T,U] fp32.
// Round 8 = round 6 (best known good, 3234us) + ONE isolated change:
//   cooperative staged h-load. Previously each WG's 6 MFMA waves redundantly
//   loaded the SAME 32KB of h from L3 every step (192KB/WG/step = 12.3MB/step
//   aggregate, ~2TB/s of L3 reads camped on four 32KB hot regions -> inflated
//   every sc1 round-trip in the step chain). Now phase A is split:
//     A1: all 8 waves load 4 chunks each (32 x 16B sc1 loads total) and
//         ds_write to LDS; waves 6-7 also prefetch x (as before).
//     A2: waves 0-5 ds_read A-fragments from LDS + 48 MFMAs.
//   L3 h-traffic drops 6x (12.3 -> 2 MB/step). One extra barrier per step.
// Everything else identical to round 6: 64 persistent WGs = 4 groups
// (16 batch rows) x 16 col-WGs (32 units); sc1 (device-coherent) relaxed
// atomics for h exchange; per-(group,step) counter + s_sleep poll by tid 0;
// out stores deferred past the counter increment.

typedef float f32x4 __attribute__((ext_vector_type(4)));
typedef short bf16x8 __attribute__((ext_vector_type(8)));
typedef unsigned long long u64;
typedef unsigned int u32;

#define MFMA16(a, b, c) __builtin_amdgcn_mfma_f32_16x16x32_bf16((a), (b), (c), 0, 0, 0)

__device__ __forceinline__ float bf2f(__hip_bfloat16 v) { return __bfloat162float(v); }

__device__ __forceinline__ void split_bf(float v, short& hi, short& lo) {
    __hip_bfloat16 h = __float2bfloat16(v);
    float rem = v - __bfloat162float(h);
    __hip_bfloat16 l = __float2bfloat16(rem);
    hi = __builtin_bit_cast(short, h);
    lo = __builtin_bit_cast(short, l);
}

struct U64x2 {
    u64 a, b;
};

// Device-coherent 16B load as two sc1 dwordx2 loads (agent scope, relaxed).
__device__ __forceinline__ bf16x8 load_frag_sc1(const __hip_bfloat16* p) {
    const u64* q = (const u64*)p;
    U64x2 t;
    t.a = __hip_atomic_load(q, __ATOMIC_RELAXED, __HIP_MEMORY_SCOPE_AGENT);
    t.b = __hip_atomic_load(q + 1, __ATOMIC_RELAXED, __HIP_MEMORY_SCOPE_AGENT);
    return __builtin_bit_cast(bf16x8, t);
}

__device__ __forceinline__ void store_pair_sc1(__hip_bfloat16* p, short e0, short e1) {
    u32 v = (u32)(unsigned short)e0 | ((u32)(unsigned short)e1 << 16);
    __hip_atomic_store((u32*)p, v, __ATOMIC_RELAXED, __HIP_MEMORY_SCOPE_AGENT);
}

// ---------------------------------------------------------------- zero scratch
__global__ void zero_kernel(float* p, int n) {
    int i = blockIdx.x * blockDim.x + threadIdx.x;
    int stride = gridDim.x * blockDim.x;
    for (; i < n; i += stride) p[i] = 0.f;
}

// ------------------------------------------------- pack weights into B-frags
// Source W [512 x 1536] fp32. Frag (tile,kk): lane l element e =
// W[kk*32 + 8*(l>>4) + e][tile*16 + (l&15)], stored hi/lo bf16 planes.
__global__ __launch_bounds__(64, 1) void pack_w_kernel(const float* __restrict__ W,
                                                       short* __restrict__ dhi,
                                                       short* __restrict__ dlo) {
    int bid = blockIdx.x;   // tile*16 + kk, 0..1535
    int lane = threadIdx.x; // 0..63
    int col = (bid >> 4) * 16 + (lane & 15);
    int kbase = (bid & 15) * 32 + (lane >> 4) * 8;
    bf16x8 vh, vl;
#pragma unroll
    for (int e = 0; e < 8; e++) {
        float v = W[(kbase + e) * 1536 + col];
        short h, l;
        split_bf(v, h, l);
        vh[e] = h;
        vl[e] = l;
    }
    *(bf16x8*)(dhi + bid * 512 + lane * 8) = vh;
    *(bf16x8*)(dlo + bid * 512 + lane * 8) = vl;
}

// ------------------------------------------------------------- x_all GEMM
// x_all[r=b*512+t][1536] = inputs[r][:512] @ kernel + bias[0], hi/lo bf16.
// Block = 4 waves, one 16-row tile; wave w handles col-tiles [24w, 24w+24).
__global__ __launch_bounds__(256, 2) void xgemm_kernel(
    const float* __restrict__ A, const short* __restrict__ wkh,
    const short* __restrict__ wkl, const float* __restrict__ bias,
    __hip_bfloat16* __restrict__ xhi, __hip_bfloat16* __restrict__ xlo, int xlo_en) {
    int rt = blockIdx.x; // 0..2047
    int wave = threadIdx.x >> 6, lane = threadIdx.x & 63;
    int arow = rt * 16 + (lane & 15);
    const float* abase = A + arow * 512 + (lane >> 4) * 8;

    f32x4 acc[24];
#pragma unroll
    for (int j = 0; j < 24; j++) acc[j] = (f32x4){0.f, 0.f, 0.f, 0.f};

#pragma unroll 1
    for (int kk = 0; kk < 16; kk++) {
        f32x4 a0 = *(const f32x4*)(abase + kk * 32);
        f32x4 a1 = *(const f32x4*)(abase + kk * 32 + 4);
        bf16x8 ah, al;
#pragma unroll
        for (int e = 0; e < 8; e++) {
            float v = (e < 4) ? a0[e] : a1[e - 4];
            short h, l;
            split_bf(v, h, l);
            ah[e] = h;
            al[e] = l;
        }
#pragma unroll
        for (int j = 0; j < 24; j++) {
            int frag = (wave * 24 + j) * 16 + kk;
            bf16x8 bh = *(const bf16x8*)(wkh + frag * 512 + lane * 8);
            bf16x8 bl = *(const bf16x8*)(wkl + frag * 512 + lane * 8);
            acc[j] = MFMA16(ah, bh, acc[j]);
            acc[j] = MFMA16(al, bh, acc[j]);
            acc[j] = MFMA16(ah, bl, acc[j]);
        }
    }
    int colin = lane & 15, r4 = (lane >> 4) * 4;
#pragma unroll
    for (int j = 0; j < 24; j++) {
        int colg = (wave * 24 + j) * 16 + colin;
        float bv = bias[colg];
#pragma unroll
        for (int r = 0; r < 4; r++) {
            float v = acc[j][r] + bv;
            int rowg = rt * 16 + r4 + r;
            short h, l;
            split_bf(v, h, l);
            xhi[rowg * 1536 + colg] = __builtin_bit_cast(__hip_bfloat16, h);
            if (xlo_en) xlo[rowg * 1536 + colg] = __builtin_bit_cast(__hip_bfloat16, l);
        }
    }
}

// ------------------------------------------------------------------ scan
// 64 blocks x 512 threads. block: g = bid&3 (batch group, rows 16g..16g+15),
// w = bid>>2 (units 32w..32w+31; col-tiles z:{2w,2w+1} r:{32+..} h:{64+..}).
// Phase A1: ALL waves cooperatively stage h (4 chunks each) into LDS; waves
// 6-7 also prefetch x[t]. Phase A2: waves 0-5 MFMA (A from LDS, R-slice in
// regs). Phase B: threads 0-255 gates, 2 units each; h stores sc1; counter
// protocol by tid 0; out stores deferred.
__global__ __launch_bounds__(512, 2) void scan_kernel(
    const __hip_bfloat16* __restrict__ xhi, const __hip_bfloat16* __restrict__ xlo,
    const short* __restrict__ wrh, const short* __restrict__ wrl,
    const float* __restrict__ bias, float* __restrict__ out,
    __hip_bfloat16* hbuf, int* cnt, int xlo_en) {
    const int bid = blockIdx.x;
    const int g = bid & 3;
    const int w = bid >> 2;
    const int tid = threadIdx.x;
    const int wave = tid >> 6;
    const int lane = tid & 63;

    __shared__ __align__(16) float pre[6][16][16];
    __shared__ __align__(16) __hip_bfloat16 xsh[2][16][104]; // padded stride
    __shared__ __align__(16) __hip_bfloat16 hsh[2][16][512]; // staged h (32KB)
    __shared__ float rb[96];

    if (tid < 96) {
        int seg = tid >> 5, u = tid & 31;
        rb[tid] = bias[1536 + seg * 512 + w * 32 + u];
    }

    // persistent B fragments (hi+lo) for waves 0-5
    bf16x8 bh[16], bl[16];
    if (wave < 6) {
        int tile = (wave >> 1) * 32 + 2 * w + (wave & 1);
#pragma unroll
        for (int kk = 0; kk < 16; kk++) {
            bh[kk] = *(const bf16x8*)(wrh + (tile * 16 + kk) * 512 + lane * 8);
            bl[kk] = *(const bf16x8*)(wrl + (tile * 16 + kk) * 512 + lane * 8);
        }
#pragma unroll
        for (int kk = 0; kk < 16; kk++) {
            asm volatile("" : "+v"(bh[kk]), "+v"(bl[kk])); // defeat remat
        }
    }

    const int grow = tid & 15; // gate thread: batch row
    const int q = tid >> 4;    // gate thread: unit pair 0..15 (tid<256)
    float h0 = 0.f, h1 = 0.f;
    const int wlane = grow + 16 * (q >> 2); // frag lane for h writes
    const int woff = (2 * q) & 7;           // element offset in frag lane

    __syncthreads();

    const int HB = 8192; // plane stride (elems): 16 kk * 64 lanes * 8
    for (int t = 0; t < 512; t++) {
        const int rpar = t & 1;
        // ---------- phase A1: cooperative h staging + x prefetch ----------
        {
            const __hip_bfloat16* hbase = hbuf + (rpar * 4 + g) * 2 * HB;
            int c0 = wave * 4;
#pragma unroll
            for (int j = 0; j < 4; j++) {
                int c = c0 + j;
                int plane = c >> 4, kk = c & 15;
                bf16x8 v = load_frag_sc1(hbase + plane * HB + kk * 512 + lane * 8);
                *(bf16x8*)&hsh[plane][kk][lane * 8] = v;
            }
        }
        if (wave >= 6) {
            int it = tid - 384; // 0..127
            int nch = xlo_en ? 384 : 192;
            for (int c = it; c < nch; c += 128) {
                int plane = c / 192;
                int rem = c % 192;
                int row_ = rem / 12;
                int cw = rem % 12;
                int seg = cw >> 2, off = cw & 3;
                int rglob = (g * 16 + row_) * 512 + t;
                const __hip_bfloat16* src =
                    (plane ? xlo : xhi) + rglob * 1536 + seg * 512 + w * 32 + off * 8;
                *(bf16x8*)&xsh[plane][row_][seg * 32 + off * 8] = *(const bf16x8*)src;
            }
        }
        __syncthreads();
        // ---------- phase A2: MFMA (A from LDS, B in regs) ----------
        if (wave < 6) {
            f32x4 aa = (f32x4){0.f, 0.f, 0.f, 0.f};
            f32x4 ab = (f32x4){0.f, 0.f, 0.f, 0.f};
            f32x4 ac = (f32x4){0.f, 0.f, 0.f, 0.f};
#pragma unroll
            for (int kk = 0; kk < 16; kk++) {
                bf16x8 ah = *(const bf16x8*)&hsh[0][kk][lane * 8];
                bf16x8 al = *(const bf16x8*)&hsh[1][kk][lane * 8];
                aa = MFMA16(ah, bh[kk], aa);
                ab = MFMA16(al, bh[kk], ab);
                ac = MFMA16(ah, bl[kk], ac);
            }
            f32x4 acc = aa + ab;
            acc = acc + ac;
            int col = lane & 15, r4 = (lane >> 4) * 4;
            *(f32x4*)&pre[wave][col][r4] = acc;
        }
        __syncthreads();
        // ---------- phase B: gates (h stores only; out deferred) ----------
        if (tid < 256) {
            const int wpar = 1 - rpar;
            __hip_bfloat16* hw =
                hbuf + ((wpar * 4 + g) * 2 + 0) * HB + w * 512 + wlane * 8 + woff;
            __hip_bfloat16* hwl = hw + HB;
            float hold[2] = {h0, h1};
            float hn[2];
#pragma unroll
            for (int j = 0; j < 2; j++) {
                int uu = 2 * q + j;
                int slot = uu >> 4, c16 = uu & 15;
                float xz = bf2f(xsh[0][grow][uu]);
                float xr = bf2f(xsh[0][grow][32 + uu]);
                float xh = bf2f(xsh[0][grow][64 + uu]);
                if (xlo_en) {
                    xz += bf2f(xsh[1][grow][uu]);
                    xr += bf2f(xsh[1][grow][32 + uu]);
                    xh += bf2f(xsh[1][grow][64 + uu]);
                }
                float rz = pre[slot][c16][grow] + rb[uu];
                float rr = pre[2 + slot][c16][grow] + rb[32 + uu];
                float rh = pre[4 + slot][c16][grow] + rb[64 + uu];
                float z = 1.f / (1.f + expf(-(xz + rz)));
                float r = 1.f / (1.f + expf(-(xr + rr)));
                float hh = tanhf(xh + r * rh);
                hn[j] = z * hold[j] + (1.f - z) * hh;
            }
            h0 = hn[0];
            h1 = hn[1];
            short hi0, lo0, hi1, lo1;
            split_bf(hn[0], hi0, lo0);
            split_bf(hn[1], hi1, lo1);
            store_pair_sc1(hw, hi0, hi1);
            store_pair_sc1(hwl, lo0, lo1);
        }
        if (t == 511) {
            if (tid < 256) {
                int obase = ((g * 16 + grow) * 512 + t) * 512 + w * 32 + 2 * q;
                out[obase] = h0;
                out[obase + 1] = h1;
            }
            break;
        }
        // barrier drains all sc1 h-stores (device-visible on completion);
        // tid0's relaxed increment then acts as a release.
        __syncthreads();
        if (tid == 0) {
            int idx = g * 512 + t;
            __hip_atomic_fetch_add(&cnt[idx], 1, __ATOMIC_RELAXED, __HIP_MEMORY_SCOPE_AGENT);
        }
        // deferred out stores: drain overlaps tid 0's poll window
        if (tid < 256) {
            int obase = ((g * 16 + grow) * 512 + t) * 512 + w * 32 + 2 * q;
            out[obase] = h0;
            out[obase + 1] = h1;
        }
        if (tid == 0) {
            int idx = g * 512 + t;
            long spins = 0;
            while (__hip_atomic_load(&cnt[idx], __ATOMIC_RELAXED, __HIP_MEMORY_SCOPE_AGENT) <
                   16) {
                if (++spins > (1L << 24)) break; // bailout (never hit if correct)
                __builtin_amdgcn_s_sleep(1);
            }
        }
        __syncthreads();
    }
}

extern "C" void kernel_launch(void* const* d_in, const int* in_sizes, int n_in,
                              void* d_out, int out_size, void* d_ws, size_t ws_size,
                              hipStream_t stream) {
    const float* inputs = (const float*)d_in[0]; // [64,512,512]
    const float* wk = (const float*)d_in[1];     // [512,1536]
    const float* wr = (const float*)d_in[2];     // [512,1536]
    const float* bias = (const float*)d_in[3];   // [2,1536]
    float* out = (float*)d_out;
    char* ws = (char*)d_ws;

    const size_t SZ_W = 512UL * 1536 * 2; // 1.5 MiB per plane
    short* wk_hi = (short*)(ws);
    short* wk_lo = (short*)(ws + SZ_W);
    short* wr_hi = (short*)(ws + 2 * SZ_W);
    short* wr_lo = (short*)(ws + 3 * SZ_W);
    __hip_bfloat16* hbuf = (__hip_bfloat16*)(ws + 4 * SZ_W); // 256 KiB
    int* cnt = (int*)(ws + 4 * SZ_W + 262144);               // 8 KiB
    char* xbase = ws + 4 * SZ_W + 262144 + 8192;
    const size_t SZ_X = 32768UL * 1536 * 2; // 96 MiB per plane
    __hip_bfloat16* xhi = (__hip_bfloat16*)xbase;
    __hip_bfloat16* xlo = (__hip_bfloat16*)(xbase + SZ_X);

    size_t need_min = (size_t)(xbase - ws) + SZ_X;
    size_t need_full = need_min + SZ_X;
    if (ws_size < need_min) return; // cannot run without scratch; fail visibly
    int xlo_en = (ws_size >= need_full) ? 1 : 0;

    zero_kernel<<<256, 256, 0, stream>>>((float*)hbuf, (262144 + 8192) / 4);
    pack_w_kernel<<<1536, 64, 0, stream>>>(wk, wk_hi, wk_lo);
    pack_w_kernel<<<1536, 64, 0, stream>>>(wr, wr_hi, wr_lo);
    xgemm_kernel<<<2048, 256, 0, stream>>>(inputs, wk_hi, wk_lo, bias, xhi, xlo, xlo_en);
    scan_kernel<<<64, 512, 0, stream>>>(xhi, xlo, wr_hi, wr_lo, bias, out, hbuf, cnt,
                                        xlo_en);
}

// Round 9
// 2556.646 us; speedup vs baseline: 1.6373x; 1.2044x over previous
//
#include <hip/hip_runtime.h>
#include <hip/hip_bf16.h>

// GRU forward: B=64, T=512, I=512, U=512, out [B,T,U] fp32.
// Round 9: tag-in-data sync protocol.
//  - h exchange: each gate thread stores ONE atomic u64 {hi0,hi1,lo0,lo1} with
//    a 2-bit tag (t%3)+1 embedded in the two lo-bf16 LSBs (error <= 2^-16).
//    Fire-and-forget: no vmcnt drain, no counter, no flag, no s_sleep.
//  - consumers: 512 staging threads each load 8 u64 (one peer chunk slice) and
//    spin until tags == ((t-1)%3)+1 -> detect IS the data load (1 L3 RT).
//    Tag mod 3 (nonzero) disambiguates stale parity data AND zero-init.
//    WAR safety: validating h_{t-1} proves all peers passed A1(t-1), so
//    overwriting h_{t-2} in the parity slot is safe (see r9 derivation).
//  - raw s_barrier + explicit lgkmcnt(0) only (3x/step): no vmcnt drains on
//    any barrier; h/out store acks float off the critical path.
//  - __launch_bounds__(512,1): VGPR cap 256 so the R-slice (128 VGPR) is truly
//    register-resident (r8's (512,2) capped at 128 and silently re-streamed
//    weights from L2 every step).
// Layout: 64 WGs = 4 groups (16 batch rows) x 16 col-WGs (32 units). Waves
// 0-5 MFMA, waves 6-7 x-prefetch (issue at A1, ds_write at A2), all 8 waves
// stage h, waves 0-3 (tid<256) gates.

typedef float f32x4 __attribute__((ext_vector_type(4)));
typedef float f32x2 __attribute__((ext_vector_type(2)));
typedef short bf16x8 __attribute__((ext_vector_type(8)));
typedef unsigned long long u64;
typedef unsigned int u32;
typedef unsigned short u16;
typedef u32 u32x4 __attribute__((ext_vector_type(4)));

#define MFMA16(a, b, c) __builtin_amdgcn_mfma_f32_16x16x32_bf16((a), (b), (c), 0, 0, 0)

__device__ __forceinline__ float bf2f(__hip_bfloat16 v) { return __bfloat162float(v); }

__device__ __forceinline__ void split_bf(float v, short& hi, short& lo) {
    __hip_bfloat16 h = __float2bfloat16(v);
    float rem = v - __bfloat162float(h);
    __hip_bfloat16 l = __float2bfloat16(rem);
    hi = __builtin_bit_cast(short, h);
    lo = __builtin_bit_cast(short, l);
}

// Raw barrier: LDS-drain only. No vmcnt drain (that's the point).
__device__ __forceinline__ void wg_barrier() {
    __builtin_amdgcn_sched_barrier(0);
    asm volatile("s_waitcnt lgkmcnt(0)" ::: "memory");
    __builtin_amdgcn_s_barrier();
    __builtin_amdgcn_sched_barrier(0);
}

// ---------------------------------------------------------------- zero scratch
__global__ void zero_kernel(float* p, int n) {
    int i = blockIdx.x * blockDim.x + threadIdx.x;
    int stride = gridDim.x * blockDim.x;
    for (; i < n; i += stride) p[i] = 0.f;
}

// ------------------------------------------------- pack weights into B-frags
// Source W [512 x 1536] fp32. Frag (tile,kk): lane l element e =
// W[kk*32 + 8*(l>>4) + e][tile*16 + (l&15)], stored hi/lo bf16 planes.
__global__ __launch_bounds__(64, 1) void pack_w_kernel(const float* __restrict__ W,
                                                       short* __restrict__ dhi,
                                                       short* __restrict__ dlo) {
    int bid = blockIdx.x;   // tile*16 + kk, 0..1535
    int lane = threadIdx.x; // 0..63
    int col = (bid >> 4) * 16 + (lane & 15);
    int kbase = (bid & 15) * 32 + (lane >> 4) * 8;
    bf16x8 vh, vl;
#pragma unroll
    for (int e = 0; e < 8; e++) {
        float v = W[(kbase + e) * 1536 + col];
        short h, l;
        split_bf(v, h, l);
        vh[e] = h;
        vl[e] = l;
    }
    *(bf16x8*)(dhi + bid * 512 + lane * 8) = vh;
    *(bf16x8*)(dlo + bid * 512 + lane * 8) = vl;
}

// ------------------------------------------------------------- x_all GEMM
__global__ __launch_bounds__(256, 2) void xgemm_kernel(
    const float* __restrict__ A, const short* __restrict__ wkh,
    const short* __restrict__ wkl, const float* __restrict__ bias,
    __hip_bfloat16* __restrict__ xhi, __hip_bfloat16* __restrict__ xlo, int xlo_en) {
    int rt = blockIdx.x; // 0..2047
    int wave = threadIdx.x >> 6, lane = threadIdx.x & 63;
    int arow = rt * 16 + (lane & 15);
    const float* abase = A + arow * 512 + (lane >> 4) * 8;

    f32x4 acc[24];
#pragma unroll
    for (int j = 0; j < 24; j++) acc[j] = (f32x4){0.f, 0.f, 0.f, 0.f};

#pragma unroll 1
    for (int kk = 0; kk < 16; kk++) {
        f32x4 a0 = *(const f32x4*)(abase + kk * 32);
        f32x4 a1 = *(const f32x4*)(abase + kk * 32 + 4);
        bf16x8 ah, al;
#pragma unroll
        for (int e = 0; e < 8; e++) {
            float v = (e < 4) ? a0[e] : a1[e - 4];
            short h, l;
            split_bf(v, h, l);
            ah[e] = h;
            al[e] = l;
        }
#pragma unroll
        for (int j = 0; j < 24; j++) {
            int frag = (wave * 24 + j) * 16 + kk;
            bf16x8 bh = *(const bf16x8*)(wkh + frag * 512 + lane * 8);
            bf16x8 bl = *(const bf16x8*)(wkl + frag * 512 + lane * 8);
            acc[j] = MFMA16(ah, bh, acc[j]);
            acc[j] = MFMA16(al, bh, acc[j]);
            acc[j] = MFMA16(ah, bl, acc[j]);
        }
    }
    int colin = lane & 15, r4 = (lane >> 4) * 4;
#pragma unroll
    for (int j = 0; j < 24; j++) {
        int colg = (wave * 24 + j) * 16 + colin;
        float bv = bias[colg];
#pragma unroll
        for (int r = 0; r < 4; r++) {
            float v = acc[j][r] + bv;
            int rowg = rt * 16 + r4 + r;
            short h, l;
            split_bf(v, h, l);
            xhi[rowg * 1536 + colg] = __builtin_bit_cast(__hip_bfloat16, h);
            if (xlo_en) xlo[rowg * 1536 + colg] = __builtin_bit_cast(__hip_bfloat16, l);
        }
    }
}

// ------------------------------------------------------------------ scan
// hbuf2 layout: [par(2)][group(4)][4096 u64]; slot s within a group:
// chunk=s>>8 (peer WG w), lane'=(s>>2)&63, epair=s&3. u64 = {hi0,hi1,lo0,lo1}
// for (row=lane'&15, units 32*chunk + 8*(lane'>>4) + 2*epair..+1), tag bits in
// lo0/lo1 LSBs. hsh u32 view: plane*4096 + s.
__global__ __launch_bounds__(512, 1) void scan_kernel(
    const __hip_bfloat16* __restrict__ xhi, const __hip_bfloat16* __restrict__ xlo,
    const short* __restrict__ wrh, const short* __restrict__ wrl,
    const float* __restrict__ bias, float* __restrict__ out,
    u64* hbuf2, int xlo_en) {
    const int bid = blockIdx.x;
    const int g = bid & 3;
    const int w = bid >> 2;
    const int tid = threadIdx.x;
    const int wave = tid >> 6;
    const int lane = tid & 63;

    __shared__ __align__(16) float pre[6][16][16];
    __shared__ __align__(16) __hip_bfloat16 xsh[2][2][16][104]; // [par][plane]
    __shared__ __align__(16) __hip_bfloat16 hsh[2][16][512];    // [plane][kk][frag]
    __shared__ float rb[96];

    if (tid < 96) rb[tid] = bias[1536 + (tid >> 5) * 512 + w * 32 + (tid & 31)];

    // persistent B fragments (hi+lo) for waves 0-5 (LB(512,1): fits in VGPRs)
    bf16x8 bh[16], bl[16];
    if (wave < 6) {
        int tile = (wave >> 1) * 32 + 2 * w + (wave & 1);
#pragma unroll
        for (int kk = 0; kk < 16; kk++) {
            bh[kk] = *(const bf16x8*)(wrh + (tile * 16 + kk) * 512 + lane * 8);
            bl[kk] = *(const bf16x8*)(wrl + (tile * 16 + kk) * 512 + lane * 8);
        }
#pragma unroll
        for (int kk = 0; kk < 16; kk++) {
            asm volatile("" : "+v"(bh[kk]), "+v"(bl[kk])); // defeat remat
        }
    } else {
        // x[0] prefetch straight into xsh[0]
        int it0 = tid - 384; // 0..127
        int nch = xlo_en ? 384 : 192;
        for (int c = it0; c < nch; c += 128) {
            int plane = c / 192, rem = c % 192;
            int row_ = rem / 12, cw = rem % 12;
            const __hip_bfloat16* src = (plane ? xlo : xhi) +
                                        (size_t)((g * 16 + row_) * 512) * 1536 +
                                        (cw >> 2) * 512 + w * 32 + (cw & 3) * 8;
            *(bf16x8*)&xsh[0][plane][row_][(cw >> 2) * 32 + (cw & 3) * 8] =
                *(const bf16x8*)src;
        }
    }

    const int grow = tid & 15; // gate thread: batch row
    const int q = tid >> 4;    // gate thread: unit pair 0..15 (tid<256)
    float h0 = 0.f, h1 = 0.f;
    const int hslot = w * 256 + (grow + 16 * (q >> 2)) * 4 + (q & 3);
    const int sbase = tid * 8; // staging slots [sbase, sbase+8)
    const int xit = tid - 384; // x-prefetch thread index (waves 6-7)

    u32* hshu = (u32*)hsh;

    __syncthreads();

    for (int t = 0; t < 512; t++) {
        const int par = t & 1;
        // ================= A1: staged, tag-validated h load =================
        u64 sv[8];
        {
            const u64* sb = hbuf2 + ((size_t)(((t - 1) & 1) * 4 + g)) * 4096 + sbase;
            if (t == 0) {
#pragma unroll
                for (int j = 0; j < 8; j++)
                    sv[j] = __hip_atomic_load(sb + j, __ATOMIC_RELAXED,
                                              __HIP_MEMORY_SCOPE_AGENT);
            } else {
                const int expv = ((t - 1) % 3) + 1;
                const u64 expm =
                    ((u64)(expv & 1) << 32) | ((u64)((expv >> 1) & 1) << 48);
                const u64 TAGM = (1ULL << 32) | (1ULL << 48);
                long spins = 0;
                while (true) {
#pragma unroll
                    for (int j = 0; j < 8; j++)
                        sv[j] = __hip_atomic_load(sb + j, __ATOMIC_RELAXED,
                                                  __HIP_MEMORY_SCOPE_AGENT);
                    u64 diff = 0;
#pragma unroll
                    for (int j = 0; j < 8; j++) diff |= (sv[j] ^ expm) & TAGM;
                    if (diff == 0) break;
                    if (++spins > (1L << 20)) break; // bailout (never hit if correct)
                }
            }
        }
        // x[t+1] loads issued here (used at A2 phase; latency hides under A1/A2)
        bf16x8 xv0, xv1, xv2;
        if (wave >= 6 && t + 1 < 512) {
            int c0 = xit, c1 = xit + 128, c2 = xit + 256;
            {
                int plane = c0 / 192, rem = c0 % 192, row_ = rem / 12, cw = rem % 12;
                xv0 = *(const bf16x8*)((plane ? xlo : xhi) +
                                       (size_t)((g * 16 + row_) * 512 + (t + 1)) * 1536 +
                                       (cw >> 2) * 512 + w * 32 + (cw & 3) * 8);
            }
            if (xlo_en || c1 < 192) {
                int plane = c1 / 192, rem = c1 % 192, row_ = rem / 12, cw = rem % 12;
                xv1 = *(const bf16x8*)((plane ? xlo : xhi) +
                                       (size_t)((g * 16 + row_) * 512 + (t + 1)) * 1536 +
                                       (cw >> 2) * 512 + w * 32 + (cw & 3) * 8);
            }
            if (xlo_en) {
                int plane = 1, rem = c2 % 192, row_ = rem / 12, cw = rem % 12;
                xv2 = *(const bf16x8*)((plane ? xlo : xhi) +
                                       (size_t)((g * 16 + row_) * 512 + (t + 1)) * 1536 +
                                       (cw >> 2) * 512 + w * 32 + (cw & 3) * 8);
            }
        }
        // unpack staged u64s into hsh (hi plane = low u32, lo plane = high u32)
        {
            u32x4 hi0v, hi1v, lo0v, lo1v;
#pragma unroll
            for (int j = 0; j < 4; j++) {
                hi0v[j] = (u32)sv[j];
                lo0v[j] = (u32)(sv[j] >> 32);
                hi1v[j] = (u32)sv[4 + j];
                lo1v[j] = (u32)(sv[4 + j] >> 32);
            }
            *(u32x4*)&hshu[sbase] = hi0v;
            *(u32x4*)&hshu[sbase + 4] = hi1v;
            *(u32x4*)&hshu[4096 + sbase] = lo0v;
            *(u32x4*)&hshu[4096 + sbase + 4] = lo1v;
        }
        wg_barrier(); // hsh ready
        // ================= A2: MFMA (waves 0-5) / x ds_write (6-7) ==========
        if (wave < 6) {
            f32x4 aa = (f32x4){0.f, 0.f, 0.f, 0.f};
            f32x4 ab = (f32x4){0.f, 0.f, 0.f, 0.f};
            f32x4 ac = (f32x4){0.f, 0.f, 0.f, 0.f};
#pragma unroll
            for (int kk = 0; kk < 16; kk++) {
                bf16x8 ah = *(const bf16x8*)&hsh[0][kk][lane * 8];
                bf16x8 al = *(const bf16x8*)&hsh[1][kk][lane * 8];
                aa = MFMA16(ah, bh[kk], aa);
                ab = MFMA16(al, bh[kk], ab);
                ac = MFMA16(ah, bl[kk], ac);
            }
            f32x4 acc = aa + ab;
            acc = acc + ac;
            *(f32x4*)&pre[wave][lane & 15][(lane >> 4) * 4] = acc;
        } else if (t + 1 < 512) {
            int npar = (t + 1) & 1;
            int c0 = xit, c1 = xit + 128, c2 = xit + 256;
            {
                int plane = c0 / 192, rem = c0 % 192, row_ = rem / 12, cw = rem % 12;
                *(bf16x8*)&xsh[npar][plane][row_][(cw >> 2) * 32 + (cw & 3) * 8] = xv0;
            }
            if (xlo_en || c1 < 192) {
                int plane = c1 / 192, rem = c1 % 192, row_ = rem / 12, cw = rem % 12;
                *(bf16x8*)&xsh[npar][plane][row_][(cw >> 2) * 32 + (cw & 3) * 8] = xv1;
            }
            if (xlo_en) {
                int plane = 1, rem = c2 % 192, row_ = rem / 12, cw = rem % 12;
                *(bf16x8*)&xsh[npar][plane][row_][(cw >> 2) * 32 + (cw & 3) * 8] = xv2;
            }
        }
        wg_barrier(); // pre + xsh[npar] ready
        // ================= B: gates (tid<256), fire-and-forget stores =======
        if (tid < 256) {
            float hold[2] = {h0, h1};
            float hn[2];
#pragma unroll
            for (int j = 0; j < 2; j++) {
                int uu = 2 * q + j;
                int sl = uu >> 4, c16 = uu & 15;
                float xz = bf2f(xsh[par][0][grow][uu]);
                float xr = bf2f(xsh[par][0][grow][32 + uu]);
                float xh = bf2f(xsh[par][0][grow][64 + uu]);
                if (xlo_en) {
                    xz += bf2f(xsh[par][1][grow][uu]);
                    xr += bf2f(xsh[par][1][grow][32 + uu]);
                    xh += bf2f(xsh[par][1][grow][64 + uu]);
                }
                float rz = pre[sl][c16][grow] + rb[uu];
                float rr = pre[2 + sl][c16][grow] + rb[32 + uu];
                float rh = pre[4 + sl][c16][grow] + rb[64 + uu];
                float z = 1.f / (1.f + expf(-(xz + rz)));
                float r = 1.f / (1.f + expf(-(xr + rr)));
                float hh = tanhf(xh + r * rh);
                hn[j] = z * hold[j] + (1.f - z) * hh;
            }
            h0 = hn[0];
            h1 = hn[1];
            if (t < 511) {
                short hi0, lo0, hi1, lo1;
                split_bf(hn[0], hi0, lo0);
                split_bf(hn[1], hi1, lo1);
                const u32 tag = (u32)(t % 3) + 1;
                u32 lo0m = ((u32)(u16)lo0 & ~1u) | (tag & 1);
                u32 lo1m = ((u32)(u16)lo1 & ~1u) | ((tag >> 1) & 1);
                u64 v = (u64)(u16)hi0 | ((u64)(u16)hi1 << 16) | ((u64)lo0m << 32) |
                        ((u64)lo1m << 48);
                __hip_atomic_store(&hbuf2[((size_t)(par * 4 + g)) * 4096 + hslot], v,
                                   __ATOMIC_RELAXED, __HIP_MEMORY_SCOPE_AGENT);
            }
            *(f32x2*)&out[((size_t)(g * 16 + grow) * 512 + t) * 512 + w * 32 + 2 * q] =
                (f32x2){h0, h1};
        }
        wg_barrier(); // pre/xsh[par] free for rewrite; hsh free for next A1
    }
}

extern "C" void kernel_launch(void* const* d_in, const int* in_sizes, int n_in,
                              void* d_out, int out_size, void* d_ws, size_t ws_size,
                              hipStream_t stream) {
    const float* inputs = (const float*)d_in[0]; // [64,512,512]
    const float* wk = (const float*)d_in[1];     // [512,1536]
    const float* wr = (const float*)d_in[2];     // [512,1536]
    const float* bias = (const float*)d_in[3];   // [2,1536]
    float* out = (float*)d_out;
    char* ws = (char*)d_ws;

    const size_t SZ_W = 512UL * 1536 * 2; // 1.5 MiB per plane
    short* wk_hi = (short*)(ws);
    short* wk_lo = (short*)(ws + SZ_W);
    short* wr_hi = (short*)(ws + 2 * SZ_W);
    short* wr_lo = (short*)(ws + 3 * SZ_W);
    u64* hbuf2 = (u64*)(ws + 4 * SZ_W); // 2 par x 4 grp x 4096 u64 = 256 KiB
    char* xbase = ws + 4 * SZ_W + 262144;
    const size_t SZ_X = 32768UL * 1536 * 2; // 96 MiB per plane
    __hip_bfloat16* xhi = (__hip_bfloat16*)xbase;
    __hip_bfloat16* xlo = (__hip_bfloat16*)(xbase + SZ_X);

    size_t need_min = (size_t)(xbase - ws) + SZ_X;
    size_t need_full = need_min + SZ_X;
    if (ws_size < need_min) return; // cannot run without scratch; fail visibly
    int xlo_en = (ws_size >= need_full) ? 1 : 0;

    zero_kernel<<<256, 256, 0, stream>>>((float*)hbuf2, 262144 / 4);
    pack_w_kernel<<<1536, 64, 0, stream>>>(wk, wk_hi, wk_lo);
    pack_w_kernel<<<1536, 64, 0, stream>>>(wr, wr_hi, wr_lo);
    xgemm_kernel<<<2048, 256, 0, stream>>>(inputs, wk_hi, wk_lo, bias, xhi, xlo, xlo_en);
    scan_kernel<<<64, 512, 0, stream>>>(xhi, xlo, wr_hi, wr_lo, bias, out, hbuf2,
                                        xlo_en);
}

// Round 10
// 2521.187 us; speedup vs baseline: 1.6604x; 1.0141x over previous
//
#include <hip/hip_runtime.h>
#include <hip/hip_bf16.h>

// GRU forward: B=64, T=512, I=512, U=512, out [B,T,U] fp32.
// Round 10 = round 9 (tag-in-data protocol, 2070us scan) + two fixes:
//  (1) conflict-free staging: per-thread slots {tid*4..+3} u {2048+tid*4..+3}
//      -> all hsh unpack writes are 16B-lane-stride ds_write_b128 (r9's
//      tid*8 layout was 32B stride = 16-way bank conflict, 18.35M cycles).
//  (2) hsh double-buffered by parity -> loop-bottom barrier removed
//      (2 barriers/step). WAR safety: A1(t+1) writes hsh[par^1] while A2(t)
//      read hsh[par]; pre/xsh overwrites happen after bar1(t+1) which gate
//      waves only reach after finishing B(t). Cross-WG tag mod 3 unchanged.
// Protocol recap: gates store h as one atomic u64 {hi0,hi1,lo0,lo1} with
// 2-bit tag (t%3)+1 in the two lo-bf16 LSBs (err<=2^-16), fire-and-forget;
// consumers spin on their 8 slots until tags match -> detect IS the load.
// Raw s_barrier + lgkmcnt(0) only (no vmcnt drain on any barrier).
// __launch_bounds__(512,1) so the R-slice stays register/AGPR-resident.

typedef float f32x4 __attribute__((ext_vector_type(4)));
typedef float f32x2 __attribute__((ext_vector_type(2)));
typedef short bf16x8 __attribute__((ext_vector_type(8)));
typedef unsigned long long u64;
typedef unsigned int u32;
typedef unsigned short u16;
typedef u32 u32x4 __attribute__((ext_vector_type(4)));

#define MFMA16(a, b, c) __builtin_amdgcn_mfma_f32_16x16x32_bf16((a), (b), (c), 0, 0, 0)

__device__ __forceinline__ float bf2f(__hip_bfloat16 v) { return __bfloat162float(v); }

__device__ __forceinline__ void split_bf(float v, short& hi, short& lo) {
    __hip_bfloat16 h = __float2bfloat16(v);
    float rem = v - __bfloat162float(h);
    __hip_bfloat16 l = __float2bfloat16(rem);
    hi = __builtin_bit_cast(short, h);
    lo = __builtin_bit_cast(short, l);
}

// Raw barrier: LDS-drain only. No vmcnt drain (that's the point).
__device__ __forceinline__ void wg_barrier() {
    __builtin_amdgcn_sched_barrier(0);
    asm volatile("s_waitcnt lgkmcnt(0)" ::: "memory");
    __builtin_amdgcn_s_barrier();
    __builtin_amdgcn_sched_barrier(0);
}

// ---------------------------------------------------------------- zero scratch
__global__ void zero_kernel(float* p, int n) {
    int i = blockIdx.x * blockDim.x + threadIdx.x;
    int stride = gridDim.x * blockDim.x;
    for (; i < n; i += stride) p[i] = 0.f;
}

// ------------------------------------------------- pack weights into B-frags
// Source W [512 x 1536] fp32. Frag (tile,kk): lane l element e =
// W[kk*32 + 8*(l>>4) + e][tile*16 + (l&15)], stored hi/lo bf16 planes.
__global__ __launch_bounds__(64, 1) void pack_w_kernel(const float* __restrict__ W,
                                                       short* __restrict__ dhi,
                                                       short* __restrict__ dlo) {
    int bid = blockIdx.x;   // tile*16 + kk, 0..1535
    int lane = threadIdx.x; // 0..63
    int col = (bid >> 4) * 16 + (lane & 15);
    int kbase = (bid & 15) * 32 + (lane >> 4) * 8;
    bf16x8 vh, vl;
#pragma unroll
    for (int e = 0; e < 8; e++) {
        float v = W[(kbase + e) * 1536 + col];
        short h, l;
        split_bf(v, h, l);
        vh[e] = h;
        vl[e] = l;
    }
    *(bf16x8*)(dhi + bid * 512 + lane * 8) = vh;
    *(bf16x8*)(dlo + bid * 512 + lane * 8) = vl;
}

// ------------------------------------------------------------- x_all GEMM
__global__ __launch_bounds__(256, 2) void xgemm_kernel(
    const float* __restrict__ A, const short* __restrict__ wkh,
    const short* __restrict__ wkl, const float* __restrict__ bias,
    __hip_bfloat16* __restrict__ xhi, __hip_bfloat16* __restrict__ xlo, int xlo_en) {
    int rt = blockIdx.x; // 0..2047
    int wave = threadIdx.x >> 6, lane = threadIdx.x & 63;
    int arow = rt * 16 + (lane & 15);
    const float* abase = A + arow * 512 + (lane >> 4) * 8;

    f32x4 acc[24];
#pragma unroll
    for (int j = 0; j < 24; j++) acc[j] = (f32x4){0.f, 0.f, 0.f, 0.f};

#pragma unroll 1
    for (int kk = 0; kk < 16; kk++) {
        f32x4 a0 = *(const f32x4*)(abase + kk * 32);
        f32x4 a1 = *(const f32x4*)(abase + kk * 32 + 4);
        bf16x8 ah, al;
#pragma unroll
        for (int e = 0; e < 8; e++) {
            float v = (e < 4) ? a0[e] : a1[e - 4];
            short h, l;
            split_bf(v, h, l);
            ah[e] = h;
            al[e] = l;
        }
#pragma unroll
        for (int j = 0; j < 24; j++) {
            int frag = (wave * 24 + j) * 16 + kk;
            bf16x8 bh = *(const bf16x8*)(wkh + frag * 512 + lane * 8);
            bf16x8 bl = *(const bf16x8*)(wkl + frag * 512 + lane * 8);
            acc[j] = MFMA16(ah, bh, acc[j]);
            acc[j] = MFMA16(al, bh, acc[j]);
            acc[j] = MFMA16(ah, bl, acc[j]);
        }
    }
    int colin = lane & 15, r4 = (lane >> 4) * 4;
#pragma unroll
    for (int j = 0; j < 24; j++) {
        int colg = (wave * 24 + j) * 16 + colin;
        float bv = bias[colg];
#pragma unroll
        for (int r = 0; r < 4; r++) {
            float v = acc[j][r] + bv;
            int rowg = rt * 16 + r4 + r;
            short h, l;
            split_bf(v, h, l);
            xhi[rowg * 1536 + colg] = __builtin_bit_cast(__hip_bfloat16, h);
            if (xlo_en) xlo[rowg * 1536 + colg] = __builtin_bit_cast(__hip_bfloat16, l);
        }
    }
}

// ------------------------------------------------------------------ scan
// hbuf2 layout: [par(2)][group(4)][4096 u64]; slot s within a group:
// chunk=s>>8 (peer WG w), lane'=(s>>2)&63, epair=s&3. u64 = {hi0,hi1,lo0,lo1}
// for (row=lane'&15, units 32*chunk + 8*(lane'>>4) + 2*epair..+1), tag bits
// in lo0/lo1 LSBs. hsh u32 view: hshu[par*8192 + plane*4096 + s].
__global__ __launch_bounds__(512, 1) void scan_kernel(
    const __hip_bfloat16* __restrict__ xhi, const __hip_bfloat16* __restrict__ xlo,
    const short* __restrict__ wrh, const short* __restrict__ wrl,
    const float* __restrict__ bias, float* __restrict__ out,
    u64* hbuf2, int xlo_en) {
    const int bid = blockIdx.x;
    const int g = bid & 3;
    const int w = bid >> 2;
    const int tid = threadIdx.x;
    const int wave = tid >> 6;
    const int lane = tid & 63;

    __shared__ __align__(16) float pre[6][16][16];
    __shared__ __align__(16) __hip_bfloat16 xsh[2][2][16][104]; // [par][plane]
    __shared__ __align__(16) __hip_bfloat16 hsh[2][2][16][512]; // [par][plane][kk][frag]
    __shared__ float rb[96];

    if (tid < 96) rb[tid] = bias[1536 + (tid >> 5) * 512 + w * 32 + (tid & 31)];

    // persistent B fragments (hi+lo) for waves 0-5 (LB(512,1): stays resident)
    bf16x8 bh[16], bl[16];
    if (wave < 6) {
        int tile = (wave >> 1) * 32 + 2 * w + (wave & 1);
#pragma unroll
        for (int kk = 0; kk < 16; kk++) {
            bh[kk] = *(const bf16x8*)(wrh + (tile * 16 + kk) * 512 + lane * 8);
            bl[kk] = *(const bf16x8*)(wrl + (tile * 16 + kk) * 512 + lane * 8);
        }
#pragma unroll
        for (int kk = 0; kk < 16; kk++) {
            asm volatile("" : "+v"(bh[kk]), "+v"(bl[kk])); // defeat remat
        }
    } else {
        // x[0] prefetch straight into xsh[0]
        int it0 = tid - 384; // 0..127
        int nch = xlo_en ? 384 : 192;
        for (int c = it0; c < nch; c += 128) {
            int plane = c / 192, rem = c % 192;
            int row_ = rem / 12, cw = rem % 12;
            const __hip_bfloat16* src = (plane ? xlo : xhi) +
                                        (size_t)((g * 16 + row_) * 512) * 1536 +
                                        (cw >> 2) * 512 + w * 32 + (cw & 3) * 8;
            *(bf16x8*)&xsh[0][plane][row_][(cw >> 2) * 32 + (cw & 3) * 8] =
                *(const bf16x8*)src;
        }
    }

    const int grow = tid & 15; // gate thread: batch row
    const int q = tid >> 4;    // gate thread: unit pair 0..15 (tid<256)
    float h0 = 0.f, h1 = 0.f;
    const int hslot = w * 256 + (grow + 16 * (q >> 2)) * 4 + (q & 3);
    const int sA = tid * 4;        // staging slots [sA, sA+4)
    const int sB = 2048 + tid * 4; // staging slots [sB, sB+4)
    const int xit = tid - 384;     // x-prefetch thread index (waves 6-7)

    u32* hshu = (u32*)hsh;

    __syncthreads();

    for (int t = 0; t < 512; t++) {
        const int par = t & 1;
        // ================= A1: staged, tag-validated h load =================
        u64 sv[8];
        {
            const u64* gb = hbuf2 + ((size_t)(((t - 1) & 1) * 4 + g)) * 4096;
            if (t == 0) {
#pragma unroll
                for (int j = 0; j < 4; j++)
                    sv[j] = __hip_atomic_load(gb + sA + j, __ATOMIC_RELAXED,
                                              __HIP_MEMORY_SCOPE_AGENT);
#pragma unroll
                for (int j = 0; j < 4; j++)
                    sv[4 + j] = __hip_atomic_load(gb + sB + j, __ATOMIC_RELAXED,
                                                  __HIP_MEMORY_SCOPE_AGENT);
            } else {
                const int expv = ((t - 1) % 3) + 1;
                const u64 expm =
                    ((u64)(expv & 1) << 32) | ((u64)((expv >> 1) & 1) << 48);
                const u64 TAGM = (1ULL << 32) | (1ULL << 48);
                long spins = 0;
                while (true) {
#pragma unroll
                    for (int j = 0; j < 4; j++)
                        sv[j] = __hip_atomic_load(gb + sA + j, __ATOMIC_RELAXED,
                                                  __HIP_MEMORY_SCOPE_AGENT);
#pragma unroll
                    for (int j = 0; j < 4; j++)
                        sv[4 + j] = __hip_atomic_load(gb + sB + j, __ATOMIC_RELAXED,
                                                      __HIP_MEMORY_SCOPE_AGENT);
                    u64 diff = 0;
#pragma unroll
                    for (int j = 0; j < 8; j++) diff |= (sv[j] ^ expm) & TAGM;
                    if (diff == 0) break;
                    if (++spins > (1L << 20)) break; // bailout (never hit if correct)
                }
            }
        }
        // x[t+1] loads issued here (latency hides under spin/unpack/MFMA)
        bf16x8 xv0, xv1, xv2;
        if (wave >= 6 && t + 1 < 512) {
            int c0 = xit, c1 = xit + 128, c2 = xit + 256;
            {
                int plane = c0 / 192, rem = c0 % 192, row_ = rem / 12, cw = rem % 12;
                xv0 = *(const bf16x8*)((plane ? xlo : xhi) +
                                       (size_t)((g * 16 + row_) * 512 + (t + 1)) * 1536 +
                                       (cw >> 2) * 512 + w * 32 + (cw & 3) * 8);
            }
            if (xlo_en || c1 < 192) {
                int plane = c1 / 192, rem = c1 % 192, row_ = rem / 12, cw = rem % 12;
                xv1 = *(const bf16x8*)((plane ? xlo : xhi) +
                                       (size_t)((g * 16 + row_) * 512 + (t + 1)) * 1536 +
                                       (cw >> 2) * 512 + w * 32 + (cw & 3) * 8);
            }
            if (xlo_en) {
                int plane = 1, rem = c2 % 192, row_ = rem / 12, cw = rem % 12;
                xv2 = *(const bf16x8*)((plane ? xlo : xhi) +
                                       (size_t)((g * 16 + row_) * 512 + (t + 1)) * 1536 +
                                       (cw >> 2) * 512 + w * 32 + (cw & 3) * 8);
            }
        }
        // unpack staged u64s into hsh[par]: all writes 16B-lane-stride b128
        {
            u32* hp = hshu + par * 8192;
            u32x4 a0, a1, b0, b1;
#pragma unroll
            for (int j = 0; j < 4; j++) {
                a0[j] = (u32)sv[j];
                b0[j] = (u32)(sv[j] >> 32);
                a1[j] = (u32)sv[4 + j];
                b1[j] = (u32)(sv[4 + j] >> 32);
            }
            *(u32x4*)&hp[sA] = a0;
            *(u32x4*)&hp[sB] = a1;
            *(u32x4*)&hp[4096 + sA] = b0;
            *(u32x4*)&hp[4096 + sB] = b1;
        }
        wg_barrier(); // hsh[par] ready
        // ================= A2: MFMA (waves 0-5) / x ds_write (6-7) ==========
        if (wave < 6) {
            f32x4 aa = (f32x4){0.f, 0.f, 0.f, 0.f};
            f32x4 ab = (f32x4){0.f, 0.f, 0.f, 0.f};
            f32x4 ac = (f32x4){0.f, 0.f, 0.f, 0.f};
#pragma unroll
            for (int kk = 0; kk < 16; kk++) {
                bf16x8 ah = *(const bf16x8*)&hsh[par][0][kk][lane * 8];
                bf16x8 al = *(const bf16x8*)&hsh[par][1][kk][lane * 8];
                aa = MFMA16(ah, bh[kk], aa);
                ab = MFMA16(al, bh[kk], ab);
                ac = MFMA16(ah, bl[kk], ac);
            }
            f32x4 acc = aa + ab;
            acc = acc + ac;
            *(f32x4*)&pre[wave][lane & 15][(lane >> 4) * 4] = acc;
        } else if (t + 1 < 512) {
            int npar = (t + 1) & 1;
            int c0 = xit, c1 = xit + 128, c2 = xit + 256;
            {
                int plane = c0 / 192, rem = c0 % 192, row_ = rem / 12, cw = rem % 12;
                *(bf16x8*)&xsh[npar][plane][row_][(cw >> 2) * 32 + (cw & 3) * 8] = xv0;
            }
            if (xlo_en || c1 < 192) {
                int plane = c1 / 192, rem = c1 % 192, row_ = rem / 12, cw = rem % 12;
                *(bf16x8*)&xsh[npar][plane][row_][(cw >> 2) * 32 + (cw & 3) * 8] = xv1;
            }
            if (xlo_en) {
                int plane = 1, rem = c2 % 192, row_ = rem / 12, cw = rem % 12;
                *(bf16x8*)&xsh[npar][plane][row_][(cw >> 2) * 32 + (cw & 3) * 8] = xv2;
            }
        }
        wg_barrier(); // pre + xsh[npar] ready
        // ================= B: gates (tid<256), fire-and-forget stores =======
        if (tid < 256) {
            float hold[2] = {h0, h1};
            float hn[2];
#pragma unroll
            for (int j = 0; j < 2; j++) {
                int uu = 2 * q + j;
                int sl = uu >> 4, c16 = uu & 15;
                float xz = bf2f(xsh[par][0][grow][uu]);
                float xr = bf2f(xsh[par][0][grow][32 + uu]);
                float xh = bf2f(xsh[par][0][grow][64 + uu]);
                if (xlo_en) {
                    xz += bf2f(xsh[par][1][grow][uu]);
                    xr += bf2f(xsh[par][1][grow][32 + uu]);
                    xh += bf2f(xsh[par][1][grow][64 + uu]);
                }
                float rz = pre[sl][c16][grow] + rb[uu];
                float rr = pre[2 + sl][c16][grow] + rb[32 + uu];
                float rh = pre[4 + sl][c16][grow] + rb[64 + uu];
                float z = 1.f / (1.f + expf(-(xz + rz)));
                float r = 1.f / (1.f + expf(-(xr + rr)));
                float hh = tanhf(xh + r * rh);
                hn[j] = z * hold[j] + (1.f - z) * hh;
            }
            h0 = hn[0];
            h1 = hn[1];
            if (t < 511) {
                short hi0, lo0, hi1, lo1;
                split_bf(hn[0], hi0, lo0);
                split_bf(hn[1], hi1, lo1);
                const u32 tag = (u32)(t % 3) + 1;
                u32 lo0m = ((u32)(u16)lo0 & ~1u) | (tag & 1);
                u32 lo1m = ((u32)(u16)lo1 & ~1u) | ((tag >> 1) & 1);
                u64 v = (u64)(u16)hi0 | ((u64)(u16)hi1 << 16) | ((u64)lo0m << 32) |
                        ((u64)lo1m << 48);
                __hip_atomic_store(&hbuf2[((size_t)(par * 4 + g)) * 4096 + hslot], v,
                                   __ATOMIC_RELAXED, __HIP_MEMORY_SCOPE_AGENT);
            }
            *(f32x2*)&out[((size_t)(g * 16 + grow) * 512 + t) * 512 + w * 32 + 2 * q] =
                (f32x2){h0, h1};
        }
        // no loop-bottom barrier: hsh is parity-double-buffered; pre/xsh
        // overwrites only happen after the NEXT bar1, which gate waves reach
        // only after finishing this B phase.
    }
}

extern "C" void kernel_launch(void* const* d_in, const int* in_sizes, int n_in,
                              void* d_out, int out_size, void* d_ws, size_t ws_size,
                              hipStream_t stream) {
    const float* inputs = (const float*)d_in[0]; // [64,512,512]
    const float* wk = (const float*)d_in[1];     // [512,1536]
    const float* wr = (const float*)d_in[2];     // [512,1536]
    const float* bias = (const float*)d_in[3];   // [2,1536]
    float* out = (float*)d_out;
    char* ws = (char*)d_ws;

    const size_t SZ_W = 512UL * 1536 * 2; // 1.5 MiB per plane
    short* wk_hi = (short*)(ws);
    short* wk_lo = (short*)(ws + SZ_W);
    short* wr_hi = (short*)(ws + 2 * SZ_W);
    short* wr_lo = (short*)(ws + 3 * SZ_W);
    u64* hbuf2 = (u64*)(ws + 4 * SZ_W); // 2 par x 4 grp x 4096 u64 = 256 KiB
    char* xbase = ws + 4 * SZ_W + 262144;
    const size_t SZ_X = 32768UL * 1536 * 2; // 96 MiB per plane
    __hip_bfloat16* xhi = (__hip_bfloat16*)xbase;
    __hip_bfloat16* xlo = (__hip_bfloat16*)(xbase + SZ_X);

    size_t need_min = (size_t)(xbase - ws) + SZ_X;
    size_t need_full = need_min + SZ_X;
    if (ws_size < need_min) return; // cannot run without scratch; fail visibly
    int xlo_en = (ws_size >= need_full) ? 1 : 0;

    zero_kernel<<<256, 256, 0, stream>>>((float*)hbuf2, 262144 / 4);
    pack_w_kernel<<<1536, 64, 0, stream>>>(wk, wk_hi, wk_lo);
    pack_w_kernel<<<1536, 64, 0, stream>>>(wr, wr_hi, wr_lo);
    xgemm_kernel<<<2048, 256, 0, stream>>>(inputs, wk_hi, wk_lo, bias, xhi, xlo, xlo_en);
    scan_kernel<<<64, 512, 0, stream>>>(xhi, xlo, wr_hi, wr_lo, bias, out, hbuf2,
                                        xlo_en);
}